// Round 1
// baseline (5583.764 us; speedup 1.0000x reference)
//
#include <hip/hip_runtime.h>
#include <hip/hip_bf16.h>
#include <cstdio>
#include <cstdint>

typedef __hip_bfloat16 bf16;
using bf16x8 = __attribute__((ext_vector_type(8))) __bf16;
using f32x4  = __attribute__((ext_vector_type(4))) float;

#define LNUM 12
#define HDIM 768
#define NHEAD 12
#define DHEAD 64
#define FFDIM 3072
#define VOCAB 21128
#define VPAD  21248
#define NBATCH 64
#define SEQ 120
#define TITLEN 20
#define MROWS (NBATCH*SEQ)     // 7680
#define NTCLS (VPAD/128)       // 166

__device__ __forceinline__ float us2f(unsigned short u) {
  union { unsigned int u; float f; } c; c.u = ((unsigned int)u) << 16; return c.f;
}
__device__ __forceinline__ unsigned short f2us(float x) {
  bf16 h = __float2bfloat16(x);
  return *reinterpret_cast<unsigned short*>(&h);
}

// ---------------------------------------------------------------------------
// GEMM: C[M,N] = epi(A[M,K](bf16) @ Bt[N,K](bf16)^T + bias)
// 128x128 tile, BK=32, 256 threads (4 waves, 2x2 of 64x64 sub-tiles)
// EPI: 0 = store bf16, 1 = exact GELU + store bf16, 2 = per-row-tile (max, sumexp) partials
// ---------------------------------------------------------------------------
template<int EPI>
__launch_bounds__(256)
__global__ void gemm_bt(const bf16* __restrict__ A, const bf16* __restrict__ Bt,
                        const float* __restrict__ bias, bf16* __restrict__ C,
                        float2* __restrict__ parts, int N, int K) {
  __shared__ __align__(16) unsigned short smA[128*32];
  __shared__ __align__(16) unsigned short smB[128*32];
  __shared__ float redA[2][64][2];
  __shared__ float redB[2][64][2];

  const int t = threadIdx.x;
  const int l = t & 63, w = t >> 6;
  const int wr = w >> 1, wc = w & 1;
  const int brow = blockIdx.y * 128;
  const int bcol = blockIdx.x * 128;

  f32x4 acc[4][4];
#pragma unroll
  for (int i = 0; i < 4; ++i)
#pragma unroll
    for (int j = 0; j < 4; ++j) acc[i][j] = (f32x4){0.f, 0.f, 0.f, 0.f};

  const int srow = t >> 2;            // 0..63
  const int scol = (t & 3) * 8;       // 0,8,16,24
  const bf16* gA0 = A  + (size_t)(brow + srow) * K + scol;
  const bf16* gA1 = gA0 + (size_t)64 * K;
  const bf16* gB0 = Bt + (size_t)(bcol + srow) * K + scol;
  const bf16* gB1 = gB0 + (size_t)64 * K;
  unsigned short* lA0 = smA + w * 512;          // wave-uniform LDS bases
  unsigned short* lA1 = smA + 2048 + w * 512;
  unsigned short* lB0 = smB + w * 512;
  unsigned short* lB1 = smB + 2048 + w * 512;

  const int aoff = (wr*64 + (l & 15))*32 + (l >> 4)*8;
  const int boff = (wc*64 + (l & 15))*32 + (l >> 4)*8;

  for (int k0 = 0; k0 < K; k0 += 32) {
    __builtin_amdgcn_global_load_lds((const __attribute__((address_space(1))) void*)(gA0 + k0),
                                     (__attribute__((address_space(3))) void*)lA0, 16, 0, 0);
    __builtin_amdgcn_global_load_lds((const __attribute__((address_space(1))) void*)(gA1 + k0),
                                     (__attribute__((address_space(3))) void*)lA1, 16, 0, 0);
    __builtin_amdgcn_global_load_lds((const __attribute__((address_space(1))) void*)(gB0 + k0),
                                     (__attribute__((address_space(3))) void*)lB0, 16, 0, 0);
    __builtin_amdgcn_global_load_lds((const __attribute__((address_space(1))) void*)(gB1 + k0),
                                     (__attribute__((address_space(3))) void*)lB1, 16, 0, 0);
    __syncthreads();                  // compiler drains vmcnt before s_barrier
    bf16x8 af[4], bg[4];
#pragma unroll
    for (int i = 0; i < 4; ++i) {
      af[i] = *reinterpret_cast<const bf16x8*>(smA + aoff + i*512);
      bg[i] = *reinterpret_cast<const bf16x8*>(smB + boff + i*512);
    }
#pragma unroll
    for (int i = 0; i < 4; ++i)
#pragma unroll
      for (int j = 0; j < 4; ++j)
        acc[i][j] = __builtin_amdgcn_mfma_f32_16x16x32_bf16(af[i], bg[j], acc[i][j], 0, 0, 0);
    __syncthreads();
  }

  if (EPI != 2) {
#pragma unroll
    for (int i = 0; i < 4; ++i) {
      const int row = brow + wr*64 + i*16 + (l >> 4)*4;
#pragma unroll
      for (int j = 0; j < 4; ++j) {
        const int col = bcol + wc*64 + j*16 + (l & 15);
        const float bv = bias[col];
#pragma unroll
        for (int r = 0; r < 4; ++r) {
          float v = acc[i][j][r] + bv;
          if (EPI == 1) v = 0.5f * v * (1.0f + erff(v * 0.70710678118f));
          C[(size_t)(row + r) * N + col] = __float2bfloat16(v);
        }
      }
    }
  } else {
    float b4[4];
#pragma unroll
    for (int j = 0; j < 4; ++j) b4[j] = bias[bcol + wc*64 + j*16 + (l & 15)];
    float vmax[4][4];
#pragma unroll
    for (int i = 0; i < 4; ++i)
#pragma unroll
      for (int r = 0; r < 4; ++r) {
        float mx = -3.0e38f;
#pragma unroll
        for (int j = 0; j < 4; ++j) mx = fmaxf(mx, acc[i][j][r] + b4[j]);
#pragma unroll
        for (int m = 1; m < 16; m <<= 1) mx = fmaxf(mx, __shfl_xor(mx, m));
        vmax[i][r] = mx;
      }
    if ((l & 15) == 0)
#pragma unroll
      for (int i = 0; i < 4; ++i)
#pragma unroll
        for (int r = 0; r < 4; ++r) redA[wr][i*16 + (l>>4)*4 + r][wc] = vmax[i][r];
    __syncthreads();
    float vsum[4][4];
#pragma unroll
    for (int i = 0; i < 4; ++i)
#pragma unroll
      for (int r = 0; r < 4; ++r) {
        const int rl = i*16 + (l>>4)*4 + r;
        const float gm = fmaxf(redA[wr][rl][0], redA[wr][rl][1]);
        vmax[i][r] = gm;
        float ss = 0.f;
#pragma unroll
        for (int j = 0; j < 4; ++j) ss += __expf(acc[i][j][r] + b4[j] - gm);
#pragma unroll
        for (int m = 1; m < 16; m <<= 1) ss += __shfl_xor(ss, m);
        vsum[i][r] = ss;
      }
    if ((l & 15) == 0)
#pragma unroll
      for (int i = 0; i < 4; ++i)
#pragma unroll
        for (int r = 0; r < 4; ++r) redB[wr][i*16 + (l>>4)*4 + r][wc] = vsum[i][r];
    __syncthreads();
    if (wc == 0 && (l & 15) == 0)
#pragma unroll
      for (int i = 0; i < 4; ++i)
#pragma unroll
        for (int r = 0; r < 4; ++r) {
          const int rl = i*16 + (l>>4)*4 + r;
          const int row = brow + wr*64 + rl;
          parts[(size_t)row * NTCLS + blockIdx.x] =
              make_float2(vmax[i][r], redB[wr][rl][0] + redB[wr][rl][1]);
        }
  }
}

// ---------------------------------------------------------------------------
// Fused attention, one block per (batch, head); prefix-causal mask inline.
// qkv: [MROWS, 2304] bf16 (q|k|v); ctx: [MROWS, 768] bf16
// ---------------------------------------------------------------------------
__launch_bounds__(256)
__global__ void attn_kernel(const bf16* __restrict__ qkv, bf16* __restrict__ ctx) {
  const int bh = blockIdx.x;
  const int b = bh / NHEAD, h = bh % NHEAD;
  __shared__ unsigned short qs[SEQ][DHEAD];
  __shared__ unsigned short kT[DHEAD][128];
  __shared__ unsigned short vs[128][DHEAD];
  __shared__ float pl[4][128];
  const int t = threadIdx.x;
  for (int e = t; e < 128*DHEAD; e += 256) {
    const int s = e >> 6, d = e & 63;
    if (s < SEQ) {
      const bf16* base = qkv + (size_t)(b*SEQ + s)*2304 + h*DHEAD + d;
      qs[s][d] = f2us(__bfloat162float(base[0]) * 0.125f);   // fold 1/sqrt(64)
      kT[d][s] = *(const unsigned short*)(base + HDIM);
      vs[s][d] = *(const unsigned short*)(base + 2*HDIM);
    } else {
      kT[d][s] = 0;
      vs[s][d] = 0;
    }
  }
  __syncthreads();
  const int w = t >> 6, l = t & 63;
  for (int i = w; i < SEQ; i += 4) {
    float s0 = 0.f, s1 = 0.f;
#pragma unroll 8
    for (int d = 0; d < DHEAD; ++d) {
      const float qv = us2f(qs[i][d]);
      s0 = fmaf(qv, us2f(kT[d][l]), s0);
      s1 = fmaf(qv, us2f(kT[d][l + 64]), s1);
    }
    const int j1 = l + 64;
    const bool a0 = (i < TITLEN) ? (l < TITLEN) : (l < TITLEN || l <= i);
    const bool a1 = (i >= TITLEN) && (j1 <= i) && (j1 < SEQ);
    s0 = a0 ? s0 : -1e30f;
    s1 = a1 ? s1 : -1e30f;
    float mx = fmaxf(s0, s1);
#pragma unroll
    for (int m = 1; m < 64; m <<= 1) mx = fmaxf(mx, __shfl_xor(mx, m));
    const float p0 = __expf(s0 - mx), p1 = __expf(s1 - mx);
    float sm = p0 + p1;
#pragma unroll
    for (int m = 1; m < 64; m <<= 1) sm += __shfl_xor(sm, m);
    const float inv = 1.0f / sm;
    pl[w][l] = p0 * inv;
    pl[w][l + 64] = p1 * inv;
    float c = 0.f;
#pragma unroll 8
    for (int j = 0; j < SEQ; ++j) c = fmaf(pl[w][j], us2f(vs[j][l]), c);
    ctx[(size_t)(b*SEQ + i)*HDIM + h*DHEAD + l] = __float2bfloat16(c);
  }
}

// ---------------------------------------------------------------------------
// Embedding gather + LN ; residual + LN
// ---------------------------------------------------------------------------
__launch_bounds__(256)
__global__ void embed_ln(const int* __restrict__ x, const float* __restrict__ wemb,
                         const float* __restrict__ pemb, const float* __restrict__ temb,
                         const float* __restrict__ lw, const float* __restrict__ lb,
                         float* __restrict__ hf, bf16* __restrict__ hb) {
  const int row = blockIdx.x;
  const int s = row % SEQ;
  const int tok = x[row];
  const int t = threadIdx.x;
  __shared__ float red[8];
  float v[3]; float sum = 0.f, sq = 0.f;
#pragma unroll
  for (int i = 0; i < 3; ++i) {
    const int idx = t + i*256;
    const float val = wemb[(size_t)tok*HDIM + idx] + pemb[s*HDIM + idx] + temb[idx];
    v[i] = val; sum += val; sq += val*val;
  }
#pragma unroll
  for (int m = 1; m < 64; m <<= 1) { sum += __shfl_xor(sum, m); sq += __shfl_xor(sq, m); }
  if ((t & 63) == 0) { red[(t>>6)*2] = sum; red[(t>>6)*2+1] = sq; }
  __syncthreads();
  sum = red[0]+red[2]+red[4]+red[6];
  sq  = red[1]+red[3]+red[5]+red[7];
  const float mean = sum * (1.0f/HDIM);
  const float rs = rsqrtf(sq*(1.0f/HDIM) - mean*mean + 1e-12f);
#pragma unroll
  for (int i = 0; i < 3; ++i) {
    const int idx = t + i*256;
    const float o = (v[i]-mean)*rs*lw[idx] + lb[idx];
    hf[(size_t)row*HDIM + idx] = o;
    hb[(size_t)row*HDIM + idx] = __float2bfloat16(o);
  }
}

__launch_bounds__(256)
__global__ void res_ln(float* __restrict__ hf, bf16* __restrict__ hb,
                       const bf16* __restrict__ add,
                       const float* __restrict__ lw, const float* __restrict__ lb) {
  const int row = blockIdx.x;
  const int t = threadIdx.x;
  __shared__ float red[8];
  float v[3]; float sum = 0.f, sq = 0.f;
#pragma unroll
  for (int i = 0; i < 3; ++i) {
    const int idx = t + i*256;
    const float val = hf[(size_t)row*HDIM + idx] + __bfloat162float(add[(size_t)row*HDIM + idx]);
    v[i] = val; sum += val; sq += val*val;
  }
#pragma unroll
  for (int m = 1; m < 64; m <<= 1) { sum += __shfl_xor(sum, m); sq += __shfl_xor(sq, m); }
  if ((t & 63) == 0) { red[(t>>6)*2] = sum; red[(t>>6)*2+1] = sq; }
  __syncthreads();
  sum = red[0]+red[2]+red[4]+red[6];
  sq  = red[1]+red[3]+red[5]+red[7];
  const float mean = sum * (1.0f/HDIM);
  const float rs = rsqrtf(sq*(1.0f/HDIM) - mean*mean + 1e-12f);
#pragma unroll
  for (int i = 0; i < 3; ++i) {
    const int idx = t + i*256;
    const float o = (v[i]-mean)*rs*lw[idx] + lb[idx];
    hf[(size_t)row*HDIM + idx] = o;
    hb[(size_t)row*HDIM + idx] = __float2bfloat16(o);
  }
}

// ---------------------------------------------------------------------------
// Transpose + fp32->bf16 convert: in [K,N] fp32 -> out [Nout,K] bf16 (rows>=N zero)
// blockIdx.z selects one of up to 4 (src,dst) pairs.
// ---------------------------------------------------------------------------
__global__ void transpose_cvt(const float* s0, const float* s1, const float* s2, const float* s3,
                              bf16* d0, bf16* d1, bf16* d2, bf16* d3,
                              int K, int N, int Nout) {
  const float* in; bf16* out;
  switch (blockIdx.z) {
    case 0: in = s0; out = d0; break;
    case 1: in = s1; out = d1; break;
    case 2: in = s2; out = d2; break;
    default: in = s3; out = d3; break;
  }
  __shared__ float tile[32][33];
  const int bx = blockIdx.x*32, by = blockIdx.y*32;
  const int tx = threadIdx.x, ty = threadIdx.y;   // (32,8)
#pragma unroll
  for (int i = 0; i < 32; i += 8) {
    const int k = by + ty + i, n = bx + tx;
    tile[ty+i][tx] = (k < K && n < N) ? in[(size_t)k*N + n] : 0.f;
  }
  __syncthreads();
#pragma unroll
  for (int i = 0; i < 32; i += 8) {
    const int n = bx + ty + i, k = by + tx;
    if (n < Nout && k < K) out[(size_t)n*K + k] = __float2bfloat16(tile[tx][ty+i]);
  }
}

// concat qkv biases per layer; padded classifier bias (-1e9 on pad)
__global__ void prep_bias(const float* __restrict__ qb, const float* __restrict__ kb,
                          const float* __restrict__ vb, const float* __restrict__ clsb,
                          float* __restrict__ qkvb, float* __restrict__ clsbp) {
  const int i = blockIdx.x*256 + threadIdx.x;
  if (i < LNUM*2304) {
    const int l = i / 2304, n = i % 2304;
    float v;
    if (n < 768) v = qb[l*768 + n];
    else if (n < 1536) v = kb[l*768 + n - 768];
    else v = vb[l*768 + n - 1536];
    qkvb[i] = v;
  }
  if (i < VPAD) clsbp[i] = (i < VOCAB) ? clsb[i] : -1e9f;
}

// merge per-tile (max,sumexp) partials -> LSE; target-logit dot; accumulate mean loss
__launch_bounds__(64)
__global__ void ce_merge(const float2* __restrict__ parts, const bf16* __restrict__ hb,
                         const bf16* __restrict__ wclsT, const float* __restrict__ clsb,
                         const int* __restrict__ y, float* __restrict__ out) {
  const int row = blockIdx.x;
  const int l = threadIdx.x;
  const int tgt = y[row];
  float tl = 0.f;
  for (int i = l; i < HDIM; i += 64)
    tl += __bfloat162float(hb[(size_t)row*HDIM + i]) * __bfloat162float(wclsT[(size_t)tgt*HDIM + i]);
#pragma unroll
  for (int m = 1; m < 64; m <<= 1) tl += __shfl_xor(tl, m);
  float mx = -3.0e38f;
  for (int i = l; i < NTCLS; i += 64) mx = fmaxf(mx, parts[(size_t)row*NTCLS + i].x);
#pragma unroll
  for (int m = 1; m < 64; m <<= 1) mx = fmaxf(mx, __shfl_xor(mx, m));
  float ss = 0.f;
  for (int i = l; i < NTCLS; i += 64) {
    const float2 p = parts[(size_t)row*NTCLS + i];
    ss += p.y * __expf(p.x - mx);
  }
#pragma unroll
  for (int m = 1; m < 64; m <<= 1) ss += __shfl_xor(ss, m);
  if (l == 0) {
    const float lse = mx + logf(ss);
    atomicAdd(out, (lse - (tl + clsb[tgt])) * (1.0f / MROWS));
  }
}

// ---------------------------------------------------------------------------
extern "C" void kernel_launch(void* const* d_in, const int* in_sizes, int n_in,
                              void* d_out, int out_size, void* d_ws, size_t ws_size,
                              hipStream_t stream) {
  const int*   x     = (const int*)d_in[0];
  const int*   y     = (const int*)d_in[1];
  const float* wemb  = (const float*)d_in[2];
  const float* pemb  = (const float*)d_in[3];
  const float* temb  = (const float*)d_in[4];
  const float* elnw  = (const float*)d_in[5];
  const float* elnb  = (const float*)d_in[6];
  const float* qw    = (const float*)d_in[7];
  const float* qb    = (const float*)d_in[8];
  const float* kw    = (const float*)d_in[9];
  const float* kb    = (const float*)d_in[10];
  const float* vw    = (const float*)d_in[11];
  const float* vb    = (const float*)d_in[12];
  const float* aow   = (const float*)d_in[13];
  const float* aob   = (const float*)d_in[14];
  const float* alnw  = (const float*)d_in[15];
  const float* alnb  = (const float*)d_in[16];
  const float* f1w   = (const float*)d_in[17];
  const float* f1b   = (const float*)d_in[18];
  const float* f2w   = (const float*)d_in[19];
  const float* f2b   = (const float*)d_in[20];
  const float* flnw  = (const float*)d_in[21];
  const float* flnb  = (const float*)d_in[22];
  const float* clsw  = (const float*)d_in[23];
  const float* clsb  = (const float*)d_in[24];

  char* p = (char*)d_ws;
  auto alloc = [&](size_t bytes) { char* r = p; p += (bytes + 255) & ~(size_t)255; return r; };
  bf16*  wqkvT = (bf16*)alloc((size_t)2304*768*2);
  bf16*  waoT  = (bf16*)alloc((size_t)768*768*2);
  bf16*  wf1T  = (bf16*)alloc((size_t)3072*768*2);
  bf16*  wf2T  = (bf16*)alloc((size_t)768*3072*2);
  bf16*  wclsT = (bf16*)alloc((size_t)VPAD*768*2);
  float* qkvb  = (float*)alloc((size_t)LNUM*2304*4);
  float* clsbp = (float*)alloc((size_t)VPAD*4);
  float* hf    = (float*)alloc((size_t)MROWS*HDIM*4);
  bf16*  hb    = (bf16*)alloc((size_t)MROWS*HDIM*2);
  bf16*  qkv   = (bf16*)alloc((size_t)MROWS*2304*2);
  bf16*  ctxb  = (bf16*)alloc((size_t)MROWS*HDIM*2);
  bf16*  tmp   = (bf16*)alloc((size_t)MROWS*HDIM*2);
  bf16*  ffh   = (bf16*)alloc((size_t)MROWS*FFDIM*2);
  float2* parts = (float2*)alloc((size_t)MROWS*NTCLS*sizeof(float2));
  const size_t needed = (size_t)(p - (char*)d_ws);
  if (needed > ws_size) {
    fprintf(stderr, "kernel_launch: ws too small (%zu > %zu)\n", needed, ws_size);
    return;
  }

  hipMemsetAsync(d_out, 0, (size_t)out_size * sizeof(float), stream);
  prep_bias<<<108, 256, 0, stream>>>(qb, kb, vb, clsb, qkvb, clsbp);
  transpose_cvt<<<dim3(VPAD/32, 768/32, 1), dim3(32,8), 0, stream>>>(
      clsw, nullptr, nullptr, nullptr, wclsT, nullptr, nullptr, nullptr, 768, VOCAB, VPAD);
  embed_ln<<<MROWS, 256, 0, stream>>>(x, wemb, pemb, temb, elnw, elnb, hf, hb);

  for (int l = 0; l < LNUM; ++l) {
    const float* qwl = qw + (size_t)l*HDIM*HDIM;
    const float* kwl = kw + (size_t)l*HDIM*HDIM;
    const float* vwl = vw + (size_t)l*HDIM*HDIM;
    const float* aowl = aow + (size_t)l*HDIM*HDIM;
    const float* f1wl = f1w + (size_t)l*HDIM*FFDIM;
    const float* f2wl = f2w + (size_t)l*FFDIM*HDIM;

    transpose_cvt<<<dim3(24, 24, 4), dim3(32,8), 0, stream>>>(
        qwl, kwl, vwl, aowl,
        wqkvT, wqkvT + 768*768, wqkvT + 2*768*768, waoT, 768, 768, 768);
    transpose_cvt<<<dim3(96, 24, 1), dim3(32,8), 0, stream>>>(
        f1wl, nullptr, nullptr, nullptr, wf1T, nullptr, nullptr, nullptr, 768, FFDIM, FFDIM);
    transpose_cvt<<<dim3(24, 96, 1), dim3(32,8), 0, stream>>>(
        f2wl, nullptr, nullptr, nullptr, wf2T, nullptr, nullptr, nullptr, FFDIM, 768, 768);

    gemm_bt<0><<<dim3(2304/128, MROWS/128), 256, 0, stream>>>(
        hb, wqkvT, qkvb + l*2304, qkv, nullptr, 2304, HDIM);
    attn_kernel<<<NBATCH*NHEAD, 256, 0, stream>>>(qkv, ctxb);
    gemm_bt<0><<<dim3(768/128, MROWS/128), 256, 0, stream>>>(
        ctxb, waoT, aob + l*HDIM, tmp, nullptr, 768, HDIM);
    res_ln<<<MROWS, 256, 0, stream>>>(hf, hb, tmp, alnw + l*HDIM, alnb + l*HDIM);
    gemm_bt<1><<<dim3(FFDIM/128, MROWS/128), 256, 0, stream>>>(
        hb, wf1T, f1b + l*FFDIM, ffh, nullptr, FFDIM, HDIM);
    gemm_bt<0><<<dim3(768/128, MROWS/128), 256, 0, stream>>>(
        ffh, wf2T, f2b + l*HDIM, tmp, nullptr, 768, FFDIM);
    res_ln<<<MROWS, 256, 0, stream>>>(hf, hb, tmp, flnw + l*HDIM, flnb + l*HDIM);
  }

  gemm_bt<2><<<dim3(NTCLS, MROWS/128), 256, 0, stream>>>(
      hb, wclsT, clsbp, nullptr, parts, VPAD, HDIM);
  ce_merge<<<MROWS, 64, 0, stream>>>(parts, hb, wclsT, clsb, y, (float*)d_out);
}

// Round 2
// 4288.444 us; speedup vs baseline: 1.3020x; 1.3020x over previous
//
#include <hip/hip_runtime.h>
#include <hip/hip_bf16.h>
#include <hip/hip_fp16.h>
#include <cstdio>
#include <cstdint>

typedef __hip_bfloat16 bf16;
using bf16x8 = __attribute__((ext_vector_type(8))) __bf16;
using f32x4  = __attribute__((ext_vector_type(4))) float;

#define LNUM 12
#define HDIM 768
#define NHEAD 12
#define DHEAD 64
#define FFDIM 3072
#define VOCAB 21128
#define VPAD  21248
#define NBATCH 64
#define SEQ 120
#define TITLEN 20
#define MROWS (NBATCH*SEQ)     // 7680
#define NTCLS (VPAD/128)       // 166

__device__ __forceinline__ float us2f(unsigned short u) {
  union { unsigned int u; float f; } c; c.u = ((unsigned int)u) << 16; return c.f;
}

// ---------------------------------------------------------------------------
// GEMM: C[M,N] = epi(A[M,K](bf16) @ Bt[N,K](bf16)^T + bias)
// 128x128 tile, BK=32, 256 threads (4 waves, 2x2 of 64x64 sub-tiles)
// Double-buffered LDS: stage(t+1) issued BEFORE compute(t); one drain/K-step.
// 1D grid with XCD-chunked + group-of-8-rows swizzle for L2 reuse.
// EPI: 0 = store bf16, 1 = exact GELU + store bf16, 2 = (max,sumexp) partials
// ---------------------------------------------------------------------------
template<int EPI>
__launch_bounds__(256)
__global__ void gemm_bt(const bf16* __restrict__ A, const bf16* __restrict__ Bt,
                        const float* __restrict__ bias, bf16* __restrict__ C,
                        float2* __restrict__ parts, int N, int K, int nbx, int nby) {
  __shared__ __align__(16) unsigned short smA[2][128*32];
  __shared__ __align__(16) unsigned short smB[2][128*32];

  // ---- block swizzle: bijective XCD chunking (m204) + row-group of 8 ----
  const int nwg = nbx * nby;
  const int orig = blockIdx.x;
  const int q8 = nwg >> 3, r8 = nwg & 7;
  const int xcd = orig & 7, lin = orig >> 3;
  const int pid = (xcd < r8 ? xcd * (q8 + 1) : r8 * (q8 + 1) + (xcd - r8) * q8) + lin;
  const int pg = 8 * nbx;
  const int g = pid / pg;
  const int rem = pid - g * pg;
  const int rows = min(8, nby - g * 8);
  const int by = g * 8 + rem % rows;
  const int bx = rem / rows;

  const int t = threadIdx.x;
  const int l = t & 63, w = t >> 6;
  const int wr = w >> 1, wc = w & 1;
  const int brow = by * 128;
  const int bcol = bx * 128;

  f32x4 acc[4][4];
#pragma unroll
  for (int i = 0; i < 4; ++i)
#pragma unroll
    for (int j = 0; j < 4; ++j) acc[i][j] = (f32x4){0.f, 0.f, 0.f, 0.f};

  const int srow = t >> 2;            // 0..63
  const int scol = (t & 3) * 8;       // 0,8,16,24
  const bf16* gA0 = A  + (size_t)(brow + srow) * K + scol;
  const bf16* gA1 = gA0 + (size_t)64 * K;
  const bf16* gB0 = Bt + (size_t)(bcol + srow) * K + scol;
  const bf16* gB1 = gB0 + (size_t)64 * K;

  const int aoff = (wr*64 + (l & 15))*32 + (l >> 4)*8;
  const int boff = (wc*64 + (l & 15))*32 + (l >> 4)*8;

  auto stage = [&](int buf, int k0) {
    __builtin_amdgcn_global_load_lds((const __attribute__((address_space(1))) void*)(gA0 + k0),
                                     (__attribute__((address_space(3))) void*)(smA[buf] + w*512), 16, 0, 0);
    __builtin_amdgcn_global_load_lds((const __attribute__((address_space(1))) void*)(gA1 + k0),
                                     (__attribute__((address_space(3))) void*)(smA[buf] + 2048 + w*512), 16, 0, 0);
    __builtin_amdgcn_global_load_lds((const __attribute__((address_space(1))) void*)(gB0 + k0),
                                     (__attribute__((address_space(3))) void*)(smB[buf] + w*512), 16, 0, 0);
    __builtin_amdgcn_global_load_lds((const __attribute__((address_space(1))) void*)(gB1 + k0),
                                     (__attribute__((address_space(3))) void*)(smB[buf] + 2048 + w*512), 16, 0, 0);
  };

  const int nk = K >> 5;
  stage(0, 0);
  __syncthreads();
  int cur = 0;
  for (int tk = 0; tk < nk; ++tk) {
    if (tk + 1 < nk) stage(cur ^ 1, (tk + 1) << 5);   // prefetch next tile first
    const unsigned short* sa = smA[cur];
    const unsigned short* sb = smB[cur];
    bf16x8 af[4], bg[4];
#pragma unroll
    for (int i = 0; i < 4; ++i) {
      af[i] = *reinterpret_cast<const bf16x8*>(sa + aoff + i*512);
      bg[i] = *reinterpret_cast<const bf16x8*>(sb + boff + i*512);
    }
#pragma unroll
    for (int i = 0; i < 4; ++i)
#pragma unroll
      for (int j = 0; j < 4; ++j)
        acc[i][j] = __builtin_amdgcn_mfma_f32_16x16x32_bf16(af[i], bg[j], acc[i][j], 0, 0, 0);
    __syncthreads();                 // drains vmcnt(0): prefetch latency hidden under MFMAs
    cur ^= 1;
  }

  if (EPI != 2) {
#pragma unroll
    for (int i = 0; i < 4; ++i) {
      const int row = brow + wr*64 + i*16 + (l >> 4)*4;
#pragma unroll
      for (int j = 0; j < 4; ++j) {
        const int col = bcol + wc*64 + j*16 + (l & 15);
        const float bv = bias[col];
#pragma unroll
        for (int r = 0; r < 4; ++r) {
          float v = acc[i][j][r] + bv;
          if (EPI == 1) v = 0.5f * v * (1.0f + erff(v * 0.70710678118f));
          C[(size_t)(row + r) * N + col] = __float2bfloat16(v);
        }
      }
    }
  } else {
    // reuse smA as reduction scratch (all LDS reads of the K-loop are done)
    float* redA = reinterpret_cast<float*>(smA);        // [2][64][2]
    float* redB = redA + 256;                           // [2][64][2]
    float b4[4];
#pragma unroll
    for (int j = 0; j < 4; ++j) b4[j] = bias[bcol + wc*64 + j*16 + (l & 15)];
    float vmax[4][4];
#pragma unroll
    for (int i = 0; i < 4; ++i)
#pragma unroll
      for (int r = 0; r < 4; ++r) {
        float mx = -3.0e38f;
#pragma unroll
        for (int j = 0; j < 4; ++j) mx = fmaxf(mx, acc[i][j][r] + b4[j]);
#pragma unroll
        for (int m = 1; m < 16; m <<= 1) mx = fmaxf(mx, __shfl_xor(mx, m));
        vmax[i][r] = mx;
      }
    if ((l & 15) == 0)
#pragma unroll
      for (int i = 0; i < 4; ++i)
#pragma unroll
        for (int r = 0; r < 4; ++r) redA[(wr*64 + i*16 + (l>>4)*4 + r)*2 + wc] = vmax[i][r];
    __syncthreads();
    float vsum[4][4];
#pragma unroll
    for (int i = 0; i < 4; ++i)
#pragma unroll
      for (int r = 0; r < 4; ++r) {
        const int rl = i*16 + (l>>4)*4 + r;
        const float gm = fmaxf(redA[(wr*64+rl)*2], redA[(wr*64+rl)*2+1]);
        vmax[i][r] = gm;
        float ss = 0.f;
#pragma unroll
        for (int j = 0; j < 4; ++j) ss += __expf(acc[i][j][r] + b4[j] - gm);
#pragma unroll
        for (int m = 1; m < 16; m <<= 1) ss += __shfl_xor(ss, m);
        vsum[i][r] = ss;
      }
    if ((l & 15) == 0)
#pragma unroll
      for (int i = 0; i < 4; ++i)
#pragma unroll
        for (int r = 0; r < 4; ++r) redB[(wr*64 + i*16 + (l>>4)*4 + r)*2 + wc] = vsum[i][r];
    __syncthreads();
    if (wc == 0 && (l & 15) == 0)
#pragma unroll
      for (int i = 0; i < 4; ++i)
#pragma unroll
        for (int r = 0; r < 4; ++r) {
          const int rl = i*16 + (l>>4)*4 + r;
          const int row = brow + wr*64 + rl;
          parts[(size_t)row * NTCLS + bx] =
              make_float2(vmax[i][r], redB[(wr*64+rl)*2] + redB[(wr*64+rl)*2+1]);
        }
  }
}

// ---------------------------------------------------------------------------
// Fused attention v2: one block (2 waves, 128 thr) per (batch, head).
// One query per lane; K/V staged as f16 in LDS (broadcast b128 reads);
// QK via __hfma2 packed dot; f32 accumulator; defer-max online softmax (T13).
// ---------------------------------------------------------------------------
__launch_bounds__(128)
__global__ void attn_kernel(const bf16* __restrict__ qkv, bf16* __restrict__ ctx) {
  const int bh = blockIdx.x;
  const int b = bh / NHEAD, h = bh % NHEAD;
  __shared__ __align__(16) __half2 hK[SEQ][DHEAD/2];   // 15 KB
  __shared__ __align__(16) __half2 hV[SEQ][DHEAD/2];   // 15 KB
  const int t = threadIdx.x;

  for (int e = t; e < SEQ*DHEAD/8; e += 128) {
    const int s = e >> 3, d = (e & 7) * 8;
    const bf16* base = qkv + (size_t)(b*SEQ + s)*2304 + h*DHEAD + d;
    bf16x8 kk = *reinterpret_cast<const bf16x8*>(base + HDIM);
    bf16x8 vv = *reinterpret_cast<const bf16x8*>(base + 2*HDIM);
    __half2 ko[4], vo[4];
#pragma unroll
    for (int c = 0; c < 4; ++c) {
      ko[c] = __floats2half2_rn((float)kk[2*c], (float)kk[2*c+1]);
      vo[c] = __floats2half2_rn((float)vv[2*c], (float)vv[2*c+1]);
    }
    *reinterpret_cast<float4*>(&hK[s][d>>1]) = *reinterpret_cast<const float4*>(ko);
    *reinterpret_cast<float4*>(&hV[s][d>>1]) = *reinterpret_cast<const float4*>(vo);
  }

  const int w = t >> 6, l = t & 63;
  const int i = w*64 + l;
  __half2 q2[32];
  if (i < SEQ) {
    const bf16* qrow = qkv + (size_t)(b*SEQ + i)*2304 + h*DHEAD;
#pragma unroll
    for (int c = 0; c < 8; ++c) {
      bf16x8 qq = *reinterpret_cast<const bf16x8*>(qrow + c*8);
#pragma unroll
      for (int e = 0; e < 4; ++e)
        q2[c*4+e] = __floats2half2_rn((float)qq[2*e]*0.125f, (float)qq[2*e+1]*0.125f);
    }
  } else {
#pragma unroll
    for (int c = 0; c < 32; ++c) q2[c] = __floats2half2_rn(0.f, 0.f);
  }
  __syncthreads();

  const int jmax = (i < TITLEN) ? TITLEN : (i + 1);
  const int jw = (w == 0) ? 64 : SEQ;
  float m = -1e30f, sum = 0.f;
  float4 acc[16];
#pragma unroll
  for (int c = 0; c < 16; ++c) acc[c] = make_float4(0.f, 0.f, 0.f, 0.f);

  for (int j = 0; j < jw; ++j) {
    const float4* kr = reinterpret_cast<const float4*>(hK[j]);
    __half2 s2 = __floats2half2_rn(0.f, 0.f);
#pragma unroll
    for (int c = 0; c < 8; ++c) {
      float4 kk4 = kr[c];
      const __half2* kp = reinterpret_cast<const __half2*>(&kk4);
      s2 = __hfma2(q2[4*c+0], kp[0], s2);
      s2 = __hfma2(q2[4*c+1], kp[1], s2);
      s2 = __hfma2(q2[4*c+2], kp[2], s2);
      s2 = __hfma2(q2[4*c+3], kp[3], s2);
    }
    float s = __low2float(s2) + __high2float(s2);
    s = (j < jmax && i < SEQ) ? s : -1e30f;
    if (__any(s > m + 8.f)) {        // defer-max: rescale only on real max growth
      const float mn = fmaxf(m, s);
      const float al = __expf(m - mn);
      sum *= al;
#pragma unroll
      for (int c = 0; c < 16; ++c) {
        acc[c].x *= al; acc[c].y *= al; acc[c].z *= al; acc[c].w *= al;
      }
      m = mn;
    }
    const float p = __expf(s - m);
    sum += p;
    const float4* vr = reinterpret_cast<const float4*>(hV[j]);
#pragma unroll
    for (int c = 0; c < 8; ++c) {
      float4 vv4 = vr[c];
      const __half2* vp = reinterpret_cast<const __half2*>(&vv4);
#pragma unroll
      for (int e = 0; e < 2; ++e) {
        const float2 lo = __half22float2(vp[2*e]);
        const float2 hi = __half22float2(vp[2*e+1]);
        float4& a = acc[c*2+e];
        a.x += p*lo.x; a.y += p*lo.y; a.z += p*hi.x; a.w += p*hi.y;
      }
    }
  }

  if (i < SEQ) {
    const float inv = 1.0f / sum;
    bf16* orow = ctx + (size_t)(b*SEQ + i)*HDIM + h*DHEAD;
#pragma unroll
    for (int c = 0; c < 8; ++c) {
      const float4 a0 = acc[c*2], a1 = acc[c*2+1];
      bf16x8 o;
      o[0] = (__bf16)(a0.x*inv); o[1] = (__bf16)(a0.y*inv);
      o[2] = (__bf16)(a0.z*inv); o[3] = (__bf16)(a0.w*inv);
      o[4] = (__bf16)(a1.x*inv); o[5] = (__bf16)(a1.y*inv);
      o[6] = (__bf16)(a1.z*inv); o[7] = (__bf16)(a1.w*inv);
      *reinterpret_cast<bf16x8*>(orow + c*8) = o;
    }
  }
}

// ---------------------------------------------------------------------------
// Embedding gather + LN ; residual + LN
// ---------------------------------------------------------------------------
__launch_bounds__(256)
__global__ void embed_ln(const int* __restrict__ x, const float* __restrict__ wemb,
                         const float* __restrict__ pemb, const float* __restrict__ temb,
                         const float* __restrict__ lw, const float* __restrict__ lb,
                         float* __restrict__ hf, bf16* __restrict__ hb) {
  const int row = blockIdx.x;
  const int s = row % SEQ;
  const int tok = x[row];
  const int t = threadIdx.x;
  __shared__ float red[8];
  float v[3]; float sum = 0.f, sq = 0.f;
#pragma unroll
  for (int i = 0; i < 3; ++i) {
    const int idx = t + i*256;
    const float val = wemb[(size_t)tok*HDIM + idx] + pemb[s*HDIM + idx] + temb[idx];
    v[i] = val; sum += val; sq += val*val;
  }
#pragma unroll
  for (int m = 1; m < 64; m <<= 1) { sum += __shfl_xor(sum, m); sq += __shfl_xor(sq, m); }
  if ((t & 63) == 0) { red[(t>>6)*2] = sum; red[(t>>6)*2+1] = sq; }
  __syncthreads();
  sum = red[0]+red[2]+red[4]+red[6];
  sq  = red[1]+red[3]+red[5]+red[7];
  const float mean = sum * (1.0f/HDIM);
  const float rs = rsqrtf(sq*(1.0f/HDIM) - mean*mean + 1e-12f);
#pragma unroll
  for (int i = 0; i < 3; ++i) {
    const int idx = t + i*256;
    const float o = (v[i]-mean)*rs*lw[idx] + lb[idx];
    hf[(size_t)row*HDIM + idx] = o;
    hb[(size_t)row*HDIM + idx] = __float2bfloat16(o);
  }
}

__launch_bounds__(256)
__global__ void res_ln(float* __restrict__ hf, bf16* __restrict__ hb,
                       const bf16* __restrict__ add,
                       const float* __restrict__ lw, const float* __restrict__ lb) {
  const int row = blockIdx.x;
  const int t = threadIdx.x;
  __shared__ float red[8];
  float v[3]; float sum = 0.f, sq = 0.f;
#pragma unroll
  for (int i = 0; i < 3; ++i) {
    const int idx = t + i*256;
    const float val = hf[(size_t)row*HDIM + idx] + __bfloat162float(add[(size_t)row*HDIM + idx]);
    v[i] = val; sum += val; sq += val*val;
  }
#pragma unroll
  for (int m = 1; m < 64; m <<= 1) { sum += __shfl_xor(sum, m); sq += __shfl_xor(sq, m); }
  if ((t & 63) == 0) { red[(t>>6)*2] = sum; red[(t>>6)*2+1] = sq; }
  __syncthreads();
  sum = red[0]+red[2]+red[4]+red[6];
  sq  = red[1]+red[3]+red[5]+red[7];
  const float mean = sum * (1.0f/HDIM);
  const float rs = rsqrtf(sq*(1.0f/HDIM) - mean*mean + 1e-12f);
#pragma unroll
  for (int i = 0; i < 3; ++i) {
    const int idx = t + i*256;
    const float o = (v[i]-mean)*rs*lw[idx] + lb[idx];
    hf[(size_t)row*HDIM + idx] = o;
    hb[(size_t)row*HDIM + idx] = __float2bfloat16(o);
  }
}

// ---------------------------------------------------------------------------
// Per-layer weight transpose+convert, all 6 matrices in one dispatch.
// id ranges: [0,2304) four 768x768 (q,k,v,ao); [2304,4608) f1; [4608,6912) f2
// ---------------------------------------------------------------------------
__global__ void transpose_layer(const float* __restrict__ qw, const float* __restrict__ kw,
                                const float* __restrict__ vw, const float* __restrict__ aow,
                                const float* __restrict__ f1w, const float* __restrict__ f2w,
                                bf16* __restrict__ wqkvT, bf16* __restrict__ waoT,
                                bf16* __restrict__ wf1T, bf16* __restrict__ wf2T) {
  int id = blockIdx.x;
  const float* in; bf16* out; int K, N, nbx;
  if (id < 2304) {
    const int z = id / 576; id -= z * 576;
    in = (z == 0) ? qw : (z == 1) ? kw : (z == 2) ? vw : aow;
    out = (z < 3) ? (wqkvT + (size_t)z*768*768) : waoT;
    K = 768; N = 768; nbx = 24;
  } else if (id < 4608) {
    id -= 2304; in = f1w; out = wf1T; K = 768; N = 3072; nbx = 96;
  } else {
    id -= 4608; in = f2w; out = wf2T; K = 3072; N = 768; nbx = 24;
  }
  const int bx = (id % nbx) * 32, by = (id / nbx) * 32;
  __shared__ float tile[32][33];
  const int tx = threadIdx.x, ty = threadIdx.y;   // (32,8)
#pragma unroll
  for (int r = 0; r < 32; r += 8)
    tile[ty+r][tx] = in[(size_t)(by + ty + r) * N + bx + tx];
  __syncthreads();
#pragma unroll
  for (int r = 0; r < 32; r += 8)
    out[(size_t)(bx + ty + r) * K + by + tx] = __float2bfloat16(tile[tx][ty+r]);
}

// Classifier transpose: in [768,VOCAB] fp32 -> out [VPAD,768] bf16 (pad rows zero)
__global__ void transpose_cls(const float* __restrict__ in, bf16* __restrict__ out) {
  __shared__ float tile[32][33];
  const int bx = blockIdx.x*32, by = blockIdx.y*32;
  const int tx = threadIdx.x, ty = threadIdx.y;   // (32,8)
#pragma unroll
  for (int r = 0; r < 32; r += 8) {
    const int n = bx + tx;
    tile[ty+r][tx] = (n < VOCAB) ? in[(size_t)(by + ty + r) * VOCAB + n] : 0.f;
  }
  __syncthreads();
#pragma unroll
  for (int r = 0; r < 32; r += 8) {
    const int n = bx + ty + r;
    if (n < VPAD) out[(size_t)n * 768 + by + tx] = __float2bfloat16(tile[tx][ty+r]);
  }
}

// concat qkv biases per layer; padded classifier bias (-1e9 on pad)
__global__ void prep_bias(const float* __restrict__ qb, const float* __restrict__ kb,
                          const float* __restrict__ vb, const float* __restrict__ clsb,
                          float* __restrict__ qkvb, float* __restrict__ clsbp) {
  const int i = blockIdx.x*256 + threadIdx.x;
  if (i < LNUM*2304) {
    const int l = i / 2304, n = i % 2304;
    float v;
    if (n < 768) v = qb[l*768 + n];
    else if (n < 1536) v = kb[l*768 + n - 768];
    else v = vb[l*768 + n - 1536];
    qkvb[i] = v;
  }
  if (i < VPAD) clsbp[i] = (i < VOCAB) ? clsb[i] : -1e9f;
}

// merge per-tile (max,sumexp) partials -> LSE; target-logit dot; accumulate mean loss
__launch_bounds__(64)
__global__ void ce_merge(const float2* __restrict__ parts, const bf16* __restrict__ hb,
                         const bf16* __restrict__ wclsT, const float* __restrict__ clsb,
                         const int* __restrict__ y, float* __restrict__ out) {
  const int row = blockIdx.x;
  const int l = threadIdx.x;
  const int tgt = y[row];
  float tl = 0.f;
  for (int i = l; i < HDIM; i += 64)
    tl += __bfloat162float(hb[(size_t)row*HDIM + i]) * __bfloat162float(wclsT[(size_t)tgt*HDIM + i]);
#pragma unroll
  for (int m = 1; m < 64; m <<= 1) tl += __shfl_xor(tl, m);
  float mx = -3.0e38f;
  for (int i = l; i < NTCLS; i += 64) mx = fmaxf(mx, parts[(size_t)row*NTCLS + i].x);
#pragma unroll
  for (int m = 1; m < 64; m <<= 1) mx = fmaxf(mx, __shfl_xor(mx, m));
  float ss = 0.f;
  for (int i = l; i < NTCLS; i += 64) {
    const float2 p = parts[(size_t)row*NTCLS + i];
    ss += p.y * __expf(p.x - mx);
  }
#pragma unroll
  for (int m = 1; m < 64; m <<= 1) ss += __shfl_xor(ss, m);
  if (l == 0) {
    const float lse = mx + logf(ss);
    atomicAdd(out, (lse - (tl + clsb[tgt])) * (1.0f / MROWS));
  }
}

// ---------------------------------------------------------------------------
extern "C" void kernel_launch(void* const* d_in, const int* in_sizes, int n_in,
                              void* d_out, int out_size, void* d_ws, size_t ws_size,
                              hipStream_t stream) {
  const int*   x     = (const int*)d_in[0];
  const int*   y     = (const int*)d_in[1];
  const float* wemb  = (const float*)d_in[2];
  const float* pemb  = (const float*)d_in[3];
  const float* temb  = (const float*)d_in[4];
  const float* elnw  = (const float*)d_in[5];
  const float* elnb  = (const float*)d_in[6];
  const float* qw    = (const float*)d_in[7];
  const float* qb    = (const float*)d_in[8];
  const float* kw    = (const float*)d_in[9];
  const float* kb    = (const float*)d_in[10];
  const float* vw    = (const float*)d_in[11];
  const float* vb    = (const float*)d_in[12];
  const float* aow   = (const float*)d_in[13];
  const float* aob   = (const float*)d_in[14];
  const float* alnw  = (const float*)d_in[15];
  const float* alnb  = (const float*)d_in[16];
  const float* f1w   = (const float*)d_in[17];
  const float* f1b   = (const float*)d_in[18];
  const float* f2w   = (const float*)d_in[19];
  const float* f2b   = (const float*)d_in[20];
  const float* flnw  = (const float*)d_in[21];
  const float* flnb  = (const float*)d_in[22];
  const float* clsw  = (const float*)d_in[23];
  const float* clsb  = (const float*)d_in[24];

  char* p = (char*)d_ws;
  auto alloc = [&](size_t bytes) { char* r = p; p += (bytes + 255) & ~(size_t)255; return r; };
  bf16*  wqkvT = (bf16*)alloc((size_t)2304*768*2);
  bf16*  waoT  = (bf16*)alloc((size_t)768*768*2);
  bf16*  wf1T  = (bf16*)alloc((size_t)3072*768*2);
  bf16*  wf2T  = (bf16*)alloc((size_t)768*3072*2);
  bf16*  wclsT = (bf16*)alloc((size_t)VPAD*768*2);
  float* qkvb  = (float*)alloc((size_t)LNUM*2304*4);
  float* clsbp = (float*)alloc((size_t)VPAD*4);
  float* hf    = (float*)alloc((size_t)MROWS*HDIM*4);
  bf16*  hb    = (bf16*)alloc((size_t)MROWS*HDIM*2);
  bf16*  qkv   = (bf16*)alloc((size_t)MROWS*2304*2);
  bf16*  ctxb  = (bf16*)alloc((size_t)MROWS*HDIM*2);
  bf16*  tmp   = (bf16*)alloc((size_t)MROWS*HDIM*2);
  bf16*  ffh   = (bf16*)alloc((size_t)MROWS*FFDIM*2);
  float2* parts = (float2*)alloc((size_t)MROWS*NTCLS*sizeof(float2));
  const size_t needed = (size_t)(p - (char*)d_ws);
  if (needed > ws_size) {
    fprintf(stderr, "kernel_launch: ws too small (%zu > %zu)\n", needed, ws_size);
    return;
  }

  hipMemsetAsync(d_out, 0, (size_t)out_size * sizeof(float), stream);
  prep_bias<<<108, 256, 0, stream>>>(qb, kb, vb, clsb, qkvb, clsbp);
  transpose_cls<<<dim3(VPAD/32, 768/32), dim3(32,8), 0, stream>>>(clsw, wclsT);
  embed_ln<<<MROWS, 256, 0, stream>>>(x, wemb, pemb, temb, elnw, elnb, hf, hb);

  for (int l = 0; l < LNUM; ++l) {
    transpose_layer<<<6912, dim3(32,8), 0, stream>>>(
        qw + (size_t)l*HDIM*HDIM, kw + (size_t)l*HDIM*HDIM,
        vw + (size_t)l*HDIM*HDIM, aow + (size_t)l*HDIM*HDIM,
        f1w + (size_t)l*HDIM*FFDIM, f2w + (size_t)l*FFDIM*HDIM,
        wqkvT, waoT, wf1T, wf2T);

    gemm_bt<0><<<18*60, 256, 0, stream>>>(hb, wqkvT, qkvb + l*2304, qkv, nullptr,
                                          2304, HDIM, 18, 60);
    attn_kernel<<<NBATCH*NHEAD, 128, 0, stream>>>(qkv, ctxb);
    gemm_bt<0><<<6*60, 256, 0, stream>>>(ctxb, waoT, aob + l*HDIM, tmp, nullptr,
                                         768, HDIM, 6, 60);
    res_ln<<<MROWS, 256, 0, stream>>>(hf, hb, tmp, alnw + l*HDIM, alnb + l*HDIM);
    gemm_bt<1><<<24*60, 256, 0, stream>>>(hb, wf1T, f1b + l*FFDIM, ffh, nullptr,
                                          FFDIM, HDIM, 24, 60);
    gemm_bt<0><<<6*60, 256, 0, stream>>>(ffh, wf2T, f2b + l*HDIM, tmp, nullptr,
                                         768, FFDIM, 6, 60);
    res_ln<<<MROWS, 256, 0, stream>>>(hf, hb, tmp, flnw + l*HDIM, flnb + l*HDIM);
  }

  gemm_bt<2><<<NTCLS*60, 256, 0, stream>>>(hb, wclsT, clsbp, nullptr, parts,
                                           VPAD, HDIM, NTCLS, 60);
  ce_merge<<<MROWS, 64, 0, stream>>>(parts, hb, wclsT, clsb, y, (float*)d_out);
}

// Round 3
// 4213.613 us; speedup vs baseline: 1.3252x; 1.0178x over previous
//
#include <hip/hip_runtime.h>
#include <hip/hip_bf16.h>
#include <hip/hip_fp16.h>
#include <cstdio>
#include <cstdint>

typedef __hip_bfloat16 bf16;
using bf16x8 = __attribute__((ext_vector_type(8))) __bf16;
using f32x4  = __attribute__((ext_vector_type(4))) float;

#define LNUM 12
#define HDIM 768
#define NHEAD 12
#define DHEAD 64
#define FFDIM 3072
#define VOCAB 21128
#define VPAD  21248
#define NBATCH 64
#define SEQ 120
#define TITLEN 20
#define MROWS (NBATCH*SEQ)     // 7680
#define NTCLS (VPAD/128)       // 166

__device__ __forceinline__ float us2f(unsigned short u) {
  union { unsigned int u; float f; } c; c.u = ((unsigned int)u) << 16; return c.f;
}

// ---------------------------------------------------------------------------
// GEMM: C[M,N] = epi(A[M,K](bf16) @ Bt[N,K](bf16)^T + bias)
// 128x128 tile, BK=32, 256 threads (4 waves, 2x2 of 64x64 sub-tiles)
// Double-buffered LDS prefetch; XCD-chunked L2 swizzle; T2 LDS XOR swizzle
// (pre-swizzled global source + swizzled ds_read — rule #21).
// EPI: 0 = store bf16, 1 = exact GELU + store bf16, 2 = (max,sumexp) partials
// ---------------------------------------------------------------------------
template<int EPI>
__launch_bounds__(256)
__global__ void gemm_bt(const bf16* __restrict__ A, const bf16* __restrict__ Bt,
                        const float* __restrict__ bias, bf16* __restrict__ C,
                        float2* __restrict__ parts, int N, int K, int nbx, int nby) {
  __shared__ __align__(16) unsigned short smA[2][128*32];
  __shared__ __align__(16) unsigned short smB[2][128*32];

  // ---- block swizzle: bijective XCD chunking (m204) + row-group of 8 ----
  const int nwg = nbx * nby;
  const int orig = blockIdx.x;
  const int q8 = nwg >> 3, r8 = nwg & 7;
  const int xcd = orig & 7, lin = orig >> 3;
  const int pid = (xcd < r8 ? xcd * (q8 + 1) : r8 * (q8 + 1) + (xcd - r8) * q8) + lin;
  const int pg = 8 * nbx;
  const int g = pid / pg;
  const int rem = pid - g * pg;
  const int rows = min(8, nby - g * 8);
  const int by = g * 8 + rem % rows;
  const int bx = rem / rows;

  const int t = threadIdx.x;
  const int l = t & 63, w = t >> 6;
  const int wr = w >> 1, wc = w & 1;
  const int brow = by * 128;
  const int bcol = bx * 128;

  f32x4 acc[4][4];
#pragma unroll
  for (int i = 0; i < 4; ++i)
#pragma unroll
    for (int j = 0; j < 4; ++j) acc[i][j] = (f32x4){0.f, 0.f, 0.f, 0.f};

  // staging: thread t owns LDS 16B slot (row=t>>2, slot=t&3) [linear dest];
  // it loads the global slot (t&3) ^ ((row>>1)&3)  [inverse-swizzled source]
  const int srow = t >> 2;                       // 0..63
  const int scol = ((t & 3) ^ ((t >> 3) & 3)) * 8;
  const bf16* gA0 = A  + (size_t)(brow + srow) * K + scol;
  const bf16* gA1 = gA0 + (size_t)64 * K;
  const bf16* gB0 = Bt + (size_t)(bcol + srow) * K + scol;
  const bf16* gB1 = gB0 + (size_t)64 * K;

  // read: LDS[row][slot ^ ((row>>1)&3)] holds global [row][slot];
  // row-strides 16/64 are ≡0 mod 8 so the XOR term is per-thread constant
  const int arow = l & 15;
  const int aslot = (l >> 4) ^ ((arow >> 1) & 3);
  const int aoff = (wr*64 + arow)*32 + aslot*8;
  const int boff = (wc*64 + arow)*32 + aslot*8;

  auto stage = [&](int buf, int k0) {
    __builtin_amdgcn_global_load_lds((const __attribute__((address_space(1))) void*)(gA0 + k0),
                                     (__attribute__((address_space(3))) void*)(smA[buf] + w*512), 16, 0, 0);
    __builtin_amdgcn_global_load_lds((const __attribute__((address_space(1))) void*)(gA1 + k0),
                                     (__attribute__((address_space(3))) void*)(smA[buf] + 2048 + w*512), 16, 0, 0);
    __builtin_amdgcn_global_load_lds((const __attribute__((address_space(1))) void*)(gB0 + k0),
                                     (__attribute__((address_space(3))) void*)(smB[buf] + w*512), 16, 0, 0);
    __builtin_amdgcn_global_load_lds((const __attribute__((address_space(1))) void*)(gB1 + k0),
                                     (__attribute__((address_space(3))) void*)(smB[buf] + 2048 + w*512), 16, 0, 0);
  };

  const int nk = K >> 5;
  stage(0, 0);
  __syncthreads();
  int cur = 0;
  for (int tk = 0; tk < nk; ++tk) {
    if (tk + 1 < nk) stage(cur ^ 1, (tk + 1) << 5);   // prefetch next tile first
    const unsigned short* sa = smA[cur];
    const unsigned short* sb = smB[cur];
    bf16x8 af[4], bg[4];
#pragma unroll
    for (int i = 0; i < 4; ++i) {
      af[i] = *reinterpret_cast<const bf16x8*>(sa + aoff + i*512);
      bg[i] = *reinterpret_cast<const bf16x8*>(sb + boff + i*512);
    }
#pragma unroll
    for (int i = 0; i < 4; ++i)
#pragma unroll
      for (int j = 0; j < 4; ++j)
        acc[i][j] = __builtin_amdgcn_mfma_f32_16x16x32_bf16(af[i], bg[j], acc[i][j], 0, 0, 0);
    __syncthreads();                 // drains vmcnt(0): prefetch latency hidden under MFMAs
    cur ^= 1;
  }

  if (EPI != 2) {
#pragma unroll
    for (int i = 0; i < 4; ++i) {
      const int row = brow + wr*64 + i*16 + (l >> 4)*4;
#pragma unroll
      for (int j = 0; j < 4; ++j) {
        const int col = bcol + wc*64 + j*16 + (l & 15);
        const float bv = bias[col];
#pragma unroll
        for (int r = 0; r < 4; ++r) {
          float v = acc[i][j][r] + bv;
          if (EPI == 1) v = 0.5f * v * (1.0f + erff(v * 0.70710678118f));
          C[(size_t)(row + r) * N + col] = __float2bfloat16(v);
        }
      }
    }
  } else {
    // reuse smA as reduction scratch (all LDS reads of the K-loop are done)
    float* redA = reinterpret_cast<float*>(smA);        // [2][64][2]
    float* redB = redA + 256;                           // [2][64][2]
    float b4[4];
#pragma unroll
    for (int j = 0; j < 4; ++j) b4[j] = bias[bcol + wc*64 + j*16 + (l & 15)];
    float vmax[4][4];
#pragma unroll
    for (int i = 0; i < 4; ++i)
#pragma unroll
      for (int r = 0; r < 4; ++r) {
        float mx = -3.0e38f;
#pragma unroll
        for (int j = 0; j < 4; ++j) mx = fmaxf(mx, acc[i][j][r] + b4[j]);
#pragma unroll
        for (int m = 1; m < 16; m <<= 1) mx = fmaxf(mx, __shfl_xor(mx, m));
        vmax[i][r] = mx;
      }
    if ((l & 15) == 0)
#pragma unroll
      for (int i = 0; i < 4; ++i)
#pragma unroll
        for (int r = 0; r < 4; ++r) redA[(wr*64 + i*16 + (l>>4)*4 + r)*2 + wc] = vmax[i][r];
    __syncthreads();
    float vsum[4][4];
#pragma unroll
    for (int i = 0; i < 4; ++i)
#pragma unroll
      for (int r = 0; r < 4; ++r) {
        const int rl = i*16 + (l>>4)*4 + r;
        const float gm = fmaxf(redA[(wr*64+rl)*2], redA[(wr*64+rl)*2+1]);
        vmax[i][r] = gm;
        float ss = 0.f;
#pragma unroll
        for (int j = 0; j < 4; ++j) ss += __expf(acc[i][j][r] + b4[j] - gm);
#pragma unroll
        for (int m = 1; m < 16; m <<= 1) ss += __shfl_xor(ss, m);
        vsum[i][r] = ss;
      }
    if ((l & 15) == 0)
#pragma unroll
      for (int i = 0; i < 4; ++i)
#pragma unroll
        for (int r = 0; r < 4; ++r) redB[(wr*64 + i*16 + (l>>4)*4 + r)*2 + wc] = vsum[i][r];
    __syncthreads();
    if (wc == 0 && (l & 15) == 0)
#pragma unroll
      for (int i = 0; i < 4; ++i)
#pragma unroll
        for (int r = 0; r < 4; ++r) {
          const int rl = i*16 + (l>>4)*4 + r;
          const int row = brow + wr*64 + rl;
          parts[(size_t)row * NTCLS + bx] =
              make_float2(vmax[i][r], redB[(wr*64+rl)*2] + redB[(wr*64+rl)*2+1]);
        }
  }
}

// ---------------------------------------------------------------------------
// Fused attention v2: one block (2 waves, 128 thr) per (batch, head).
// One query per lane; K/V staged as f16 in LDS (broadcast b128 reads);
// QK via __hfma2 packed dot; f32 accumulator; defer-max online softmax (T13).
// ---------------------------------------------------------------------------
__launch_bounds__(128)
__global__ void attn_kernel(const bf16* __restrict__ qkv, bf16* __restrict__ ctx) {
  const int bh = blockIdx.x;
  const int b = bh / NHEAD, h = bh % NHEAD;
  __shared__ __align__(16) __half2 hK[SEQ][DHEAD/2];   // 15 KB
  __shared__ __align__(16) __half2 hV[SEQ][DHEAD/2];   // 15 KB
  const int t = threadIdx.x;

  for (int e = t; e < SEQ*DHEAD/8; e += 128) {
    const int s = e >> 3, d = (e & 7) * 8;
    const bf16* base = qkv + (size_t)(b*SEQ + s)*2304 + h*DHEAD + d;
    bf16x8 kk = *reinterpret_cast<const bf16x8*>(base + HDIM);
    bf16x8 vv = *reinterpret_cast<const bf16x8*>(base + 2*HDIM);
    __half2 ko[4], vo[4];
#pragma unroll
    for (int c = 0; c < 4; ++c) {
      ko[c] = __floats2half2_rn((float)kk[2*c], (float)kk[2*c+1]);
      vo[c] = __floats2half2_rn((float)vv[2*c], (float)vv[2*c+1]);
    }
    *reinterpret_cast<float4*>(&hK[s][d>>1]) = *reinterpret_cast<const float4*>(ko);
    *reinterpret_cast<float4*>(&hV[s][d>>1]) = *reinterpret_cast<const float4*>(vo);
  }

  const int w = t >> 6, l = t & 63;
  const int i = w*64 + l;
  __half2 q2[32];
  if (i < SEQ) {
    const bf16* qrow = qkv + (size_t)(b*SEQ + i)*2304 + h*DHEAD;
#pragma unroll
    for (int c = 0; c < 8; ++c) {
      bf16x8 qq = *reinterpret_cast<const bf16x8*>(qrow + c*8);
#pragma unroll
      for (int e = 0; e < 4; ++e)
        q2[c*4+e] = __floats2half2_rn((float)qq[2*e]*0.125f, (float)qq[2*e+1]*0.125f);
    }
  } else {
#pragma unroll
    for (int c = 0; c < 32; ++c) q2[c] = __floats2half2_rn(0.f, 0.f);
  }
  __syncthreads();

  const int jmax = (i < TITLEN) ? TITLEN : (i + 1);
  const int jw = (w == 0) ? 64 : SEQ;
  float m = -1e30f, sum = 0.f;
  float4 acc[16];
#pragma unroll
  for (int c = 0; c < 16; ++c) acc[c] = make_float4(0.f, 0.f, 0.f, 0.f);

  for (int j = 0; j < jw; ++j) {
    const float4* kr = reinterpret_cast<const float4*>(hK[j]);
    __half2 s2 = __floats2half2_rn(0.f, 0.f);
#pragma unroll
    for (int c = 0; c < 8; ++c) {
      float4 kk4 = kr[c];
      const __half2* kp = reinterpret_cast<const __half2*>(&kk4);
      s2 = __hfma2(q2[4*c+0], kp[0], s2);
      s2 = __hfma2(q2[4*c+1], kp[1], s2);
      s2 = __hfma2(q2[4*c+2], kp[2], s2);
      s2 = __hfma2(q2[4*c+3], kp[3], s2);
    }
    float s = __low2float(s2) + __high2float(s2);
    s = (j < jmax && i < SEQ) ? s : -1e30f;
    if (__any(s > m + 8.f)) {        // defer-max: rescale only on real max growth
      const float mn = fmaxf(m, s);
      const float al = __expf(m - mn);
      sum *= al;
#pragma unroll
      for (int c = 0; c < 16; ++c) {
        acc[c].x *= al; acc[c].y *= al; acc[c].z *= al; acc[c].w *= al;
      }
      m = mn;
    }
    const float p = __expf(s - m);
    sum += p;
    const float4* vr = reinterpret_cast<const float4*>(hV[j]);
#pragma unroll
    for (int c = 0; c < 8; ++c) {
      float4 vv4 = vr[c];
      const __half2* vp = reinterpret_cast<const __half2*>(&vv4);
#pragma unroll
      for (int e = 0; e < 2; ++e) {
        const float2 lo = __half22float2(vp[2*e]);
        const float2 hi = __half22float2(vp[2*e+1]);
        float4& a = acc[c*2+e];
        a.x += p*lo.x; a.y += p*lo.y; a.z += p*hi.x; a.w += p*hi.y;
      }
    }
  }

  if (i < SEQ) {
    const float inv = 1.0f / sum;
    bf16* orow = ctx + (size_t)(b*SEQ + i)*HDIM + h*DHEAD;
#pragma unroll
    for (int c = 0; c < 8; ++c) {
      const float4 a0 = acc[c*2], a1 = acc[c*2+1];
      bf16x8 o;
      o[0] = (__bf16)(a0.x*inv); o[1] = (__bf16)(a0.y*inv);
      o[2] = (__bf16)(a0.z*inv); o[3] = (__bf16)(a0.w*inv);
      o[4] = (__bf16)(a1.x*inv); o[5] = (__bf16)(a1.y*inv);
      o[6] = (__bf16)(a1.z*inv); o[7] = (__bf16)(a1.w*inv);
      *reinterpret_cast<bf16x8*>(orow + c*8) = o;
    }
  }
}

// ---------------------------------------------------------------------------
// Embedding gather + LN ; residual + LN
// ---------------------------------------------------------------------------
__launch_bounds__(256)
__global__ void embed_ln(const int* __restrict__ x, const float* __restrict__ wemb,
                         const float* __restrict__ pemb, const float* __restrict__ temb,
                         const float* __restrict__ lw, const float* __restrict__ lb,
                         float* __restrict__ hf, bf16* __restrict__ hb) {
  const int row = blockIdx.x;
  const int s = row % SEQ;
  const int tok = x[row];
  const int t = threadIdx.x;
  __shared__ float red[8];
  float v[3]; float sum = 0.f, sq = 0.f;
#pragma unroll
  for (int i = 0; i < 3; ++i) {
    const int idx = t + i*256;
    const float val = wemb[(size_t)tok*HDIM + idx] + pemb[s*HDIM + idx] + temb[idx];
    v[i] = val; sum += val; sq += val*val;
  }
#pragma unroll
  for (int m = 1; m < 64; m <<= 1) { sum += __shfl_xor(sum, m); sq += __shfl_xor(sq, m); }
  if ((t & 63) == 0) { red[(t>>6)*2] = sum; red[(t>>6)*2+1] = sq; }
  __syncthreads();
  sum = red[0]+red[2]+red[4]+red[6];
  sq  = red[1]+red[3]+red[5]+red[7];
  const float mean = sum * (1.0f/HDIM);
  const float rs = rsqrtf(sq*(1.0f/HDIM) - mean*mean + 1e-12f);
#pragma unroll
  for (int i = 0; i < 3; ++i) {
    const int idx = t + i*256;
    const float o = (v[i]-mean)*rs*lw[idx] + lb[idx];
    hf[(size_t)row*HDIM + idx] = o;
    hb[(size_t)row*HDIM + idx] = __float2bfloat16(o);
  }
}

__launch_bounds__(256)
__global__ void res_ln(float* __restrict__ hf, bf16* __restrict__ hb,
                       const bf16* __restrict__ add,
                       const float* __restrict__ lw, const float* __restrict__ lb) {
  const int row = blockIdx.x;
  const int t = threadIdx.x;
  __shared__ float red[8];
  float v[3]; float sum = 0.f, sq = 0.f;
#pragma unroll
  for (int i = 0; i < 3; ++i) {
    const int idx = t + i*256;
    const float val = hf[(size_t)row*HDIM + idx] + __bfloat162float(add[(size_t)row*HDIM + idx]);
    v[i] = val; sum += val; sq += val*val;
  }
#pragma unroll
  for (int m = 1; m < 64; m <<= 1) { sum += __shfl_xor(sum, m); sq += __shfl_xor(sq, m); }
  if ((t & 63) == 0) { red[(t>>6)*2] = sum; red[(t>>6)*2+1] = sq; }
  __syncthreads();
  sum = red[0]+red[2]+red[4]+red[6];
  sq  = red[1]+red[3]+red[5]+red[7];
  const float mean = sum * (1.0f/HDIM);
  const float rs = rsqrtf(sq*(1.0f/HDIM) - mean*mean + 1e-12f);
#pragma unroll
  for (int i = 0; i < 3; ++i) {
    const int idx = t + i*256;
    const float o = (v[i]-mean)*rs*lw[idx] + lb[idx];
    hf[(size_t)row*HDIM + idx] = o;
    hb[(size_t)row*HDIM + idx] = __float2bfloat16(o);
  }
}

// ---------------------------------------------------------------------------
// Per-layer weight transpose+convert, all 6 matrices in one dispatch.
// id ranges: [0,2304) four 768x768 (q,k,v,ao); [2304,4608) f1; [4608,6912) f2
// ---------------------------------------------------------------------------
__global__ void transpose_layer(const float* __restrict__ qw, const float* __restrict__ kw,
                                const float* __restrict__ vw, const float* __restrict__ aow,
                                const float* __restrict__ f1w, const float* __restrict__ f2w,
                                bf16* __restrict__ wqkvT, bf16* __restrict__ waoT,
                                bf16* __restrict__ wf1T, bf16* __restrict__ wf2T) {
  int id = blockIdx.x;
  const float* in; bf16* out; int K, N, nbx;
  if (id < 2304) {
    const int z = id / 576; id -= z * 576;
    in = (z == 0) ? qw : (z == 1) ? kw : (z == 2) ? vw : aow;
    out = (z < 3) ? (wqkvT + (size_t)z*768*768) : waoT;
    K = 768; N = 768; nbx = 24;
  } else if (id < 4608) {
    id -= 2304; in = f1w; out = wf1T; K = 768; N = 3072; nbx = 96;
  } else {
    id -= 4608; in = f2w; out = wf2T; K = 3072; N = 768; nbx = 24;
  }
  const int bx = (id % nbx) * 32, by = (id / nbx) * 32;
  __shared__ float tile[32][33];
  const int tx = threadIdx.x, ty = threadIdx.y;   // (32,8)
#pragma unroll
  for (int r = 0; r < 32; r += 8)
    tile[ty+r][tx] = in[(size_t)(by + ty + r) * N + bx + tx];
  __syncthreads();
#pragma unroll
  for (int r = 0; r < 32; r += 8)
    out[(size_t)(bx + ty + r) * K + by + tx] = __float2bfloat16(tile[tx][ty+r]);
}

// Classifier transpose: in [768,VOCAB] fp32 -> out [VPAD,768] bf16 (pad rows zero)
__global__ void transpose_cls(const float* __restrict__ in, bf16* __restrict__ out) {
  __shared__ float tile[32][33];
  const int bx = blockIdx.x*32, by = blockIdx.y*32;
  const int tx = threadIdx.x, ty = threadIdx.y;   // (32,8)
#pragma unroll
  for (int r = 0; r < 32; r += 8) {
    const int n = bx + tx;
    tile[ty+r][tx] = (n < VOCAB) ? in[(size_t)(by + ty + r) * VOCAB + n] : 0.f;
  }
  __syncthreads();
#pragma unroll
  for (int r = 0; r < 32; r += 8) {
    const int n = bx + ty + r;
    if (n < VPAD) out[(size_t)n * 768 + by + tx] = __float2bfloat16(tile[tx][ty+r]);
  }
}

// concat qkv biases per layer; padded classifier bias (-1e9 on pad)
__global__ void prep_bias(const float* __restrict__ qb, const float* __restrict__ kb,
                          const float* __restrict__ vb, const float* __restrict__ clsb,
                          float* __restrict__ qkvb, float* __restrict__ clsbp) {
  const int i = blockIdx.x*256 + threadIdx.x;
  if (i < LNUM*2304) {
    const int l = i / 2304, n = i % 2304;
    float v;
    if (n < 768) v = qb[l*768 + n];
    else if (n < 1536) v = kb[l*768 + n - 768];
    else v = vb[l*768 + n - 1536];
    qkvb[i] = v;
  }
  if (i < VPAD) clsbp[i] = (i < VOCAB) ? clsb[i] : -1e9f;
}

// merge per-tile (max,sumexp) partials -> LSE; target-logit dot; accumulate mean loss
__launch_bounds__(64)
__global__ void ce_merge(const float2* __restrict__ parts, const bf16* __restrict__ hb,
                         const bf16* __restrict__ wclsT, const float* __restrict__ clsb,
                         const int* __restrict__ y, float* __restrict__ out) {
  const int row = blockIdx.x;
  const int l = threadIdx.x;
  const int tgt = y[row];
  float tl = 0.f;
  for (int i = l; i < HDIM; i += 64)
    tl += __bfloat162float(hb[(size_t)row*HDIM + i]) * __bfloat162float(wclsT[(size_t)tgt*HDIM + i]);
#pragma unroll
  for (int m = 1; m < 64; m <<= 1) tl += __shfl_xor(tl, m);
  float mx = -3.0e38f;
  for (int i = l; i < NTCLS; i += 64) mx = fmaxf(mx, parts[(size_t)row*NTCLS + i].x);
#pragma unroll
  for (int m = 1; m < 64; m <<= 1) mx = fmaxf(mx, __shfl_xor(mx, m));
  float ss = 0.f;
  for (int i = l; i < NTCLS; i += 64) {
    const float2 p = parts[(size_t)row*NTCLS + i];
    ss += p.y * __expf(p.x - mx);
  }
#pragma unroll
  for (int m = 1; m < 64; m <<= 1) ss += __shfl_xor(ss, m);
  if (l == 0) {
    const float lse = mx + logf(ss);
    atomicAdd(out, (lse - (tl + clsb[tgt])) * (1.0f / MROWS));
  }
}

// ---------------------------------------------------------------------------
extern "C" void kernel_launch(void* const* d_in, const int* in_sizes, int n_in,
                              void* d_out, int out_size, void* d_ws, size_t ws_size,
                              hipStream_t stream) {
  const int*   x     = (const int*)d_in[0];
  const int*   y     = (const int*)d_in[1];
  const float* wemb  = (const float*)d_in[2];
  const float* pemb  = (const float*)d_in[3];
  const float* temb  = (const float*)d_in[4];
  const float* elnw  = (const float*)d_in[5];
  const float* elnb  = (const float*)d_in[6];
  const float* qw    = (const float*)d_in[7];
  const float* qb    = (const float*)d_in[8];
  const float* kw    = (const float*)d_in[9];
  const float* kb    = (const float*)d_in[10];
  const float* vw    = (const float*)d_in[11];
  const float* vb    = (const float*)d_in[12];
  const float* aow   = (const float*)d_in[13];
  const float* aob   = (const float*)d_in[14];
  const float* alnw  = (const float*)d_in[15];
  const float* alnb  = (const float*)d_in[16];
  const float* f1w   = (const float*)d_in[17];
  const float* f1b   = (const float*)d_in[18];
  const float* f2w   = (const float*)d_in[19];
  const float* f2b   = (const float*)d_in[20];
  const float* flnw  = (const float*)d_in[21];
  const float* flnb  = (const float*)d_in[22];
  const float* clsw  = (const float*)d_in[23];
  const float* clsb  = (const float*)d_in[24];

  char* p = (char*)d_ws;
  auto alloc = [&](size_t bytes) { char* r = p; p += (bytes + 255) & ~(size_t)255; return r; };
  bf16*  wqkvT = (bf16*)alloc((size_t)2304*768*2);
  bf16*  waoT  = (bf16*)alloc((size_t)768*768*2);
  bf16*  wf1T  = (bf16*)alloc((size_t)3072*768*2);
  bf16*  wf2T  = (bf16*)alloc((size_t)768*3072*2);
  bf16*  wclsT = (bf16*)alloc((size_t)VPAD*768*2);
  float* qkvb  = (float*)alloc((size_t)LNUM*2304*4);
  float* clsbp = (float*)alloc((size_t)VPAD*4);
  float* hf    = (float*)alloc((size_t)MROWS*HDIM*4);
  bf16*  hb    = (bf16*)alloc((size_t)MROWS*HDIM*2);
  bf16*  qkv   = (bf16*)alloc((size_t)MROWS*2304*2);
  bf16*  ctxb  = (bf16*)alloc((size_t)MROWS*HDIM*2);
  bf16*  tmp   = (bf16*)alloc((size_t)MROWS*HDIM*2);
  bf16*  ffh   = (bf16*)alloc((size_t)MROWS*FFDIM*2);
  float2* parts = (float2*)alloc((size_t)MROWS*NTCLS*sizeof(float2));
  const size_t needed = (size_t)(p - (char*)d_ws);
  if (needed > ws_size) {
    fprintf(stderr, "kernel_launch: ws too small (%zu > %zu)\n", needed, ws_size);
    return;
  }

  hipMemsetAsync(d_out, 0, (size_t)out_size * sizeof(float), stream);
  prep_bias<<<108, 256, 0, stream>>>(qb, kb, vb, clsb, qkvb, clsbp);
  transpose_cls<<<dim3(VPAD/32, 768/32), dim3(32,8), 0, stream>>>(clsw, wclsT);
  embed_ln<<<MROWS, 256, 0, stream>>>(x, wemb, pemb, temb, elnw, elnb, hf, hb);

  for (int l = 0; l < LNUM; ++l) {
    transpose_layer<<<6912, dim3(32,8), 0, stream>>>(
        qw + (size_t)l*HDIM*HDIM, kw + (size_t)l*HDIM*HDIM,
        vw + (size_t)l*HDIM*HDIM, aow + (size_t)l*HDIM*HDIM,
        f1w + (size_t)l*HDIM*FFDIM, f2w + (size_t)l*FFDIM*HDIM,
        wqkvT, waoT, wf1T, wf2T);

    gemm_bt<0><<<18*60, 256, 0, stream>>>(hb, wqkvT, qkvb + l*2304, qkv, nullptr,
                                          2304, HDIM, 18, 60);
    attn_kernel<<<NBATCH*NHEAD, 128, 0, stream>>>(qkv, ctxb);
    gemm_bt<0><<<6*60, 256, 0, stream>>>(ctxb, waoT, aob + l*HDIM, tmp, nullptr,
                                         768, HDIM, 6, 60);
    res_ln<<<MROWS, 256, 0, stream>>>(hf, hb, tmp, alnw + l*HDIM, alnb + l*HDIM);
    gemm_bt<1><<<24*60, 256, 0, stream>>>(hb, wf1T, f1b + l*FFDIM, ffh, nullptr,
                                          FFDIM, HDIM, 24, 60);
    gemm_bt<0><<<6*60, 256, 0, stream>>>(ffh, wf2T, f2b + l*HDIM, tmp, nullptr,
                                         768, FFDIM, 6, 60);
    res_ln<<<MROWS, 256, 0, stream>>>(hf, hb, tmp, flnw + l*HDIM, flnb + l*HDIM);
  }

  gemm_bt<2><<<NTCLS*60, 256, 0, stream>>>(hb, wclsT, clsbp, nullptr, parts,
                                           VPAD, HDIM, NTCLS, 60);
  ce_merge<<<MROWS, 64, 0, stream>>>(parts, hb, wclsT, clsb, y, (float*)d_out);
}